// Round 1
// baseline (316.213 us; speedup 1.0000x reference)
//
#include <hip/hip_runtime.h>

#define BB 8
#define NN 1024
#define CC 128
#define GG 4
#define LL 8
#define HD 16
#define GD 64   // GG*HD

// ---------------- Kernel A: projections q/k/v ----------------
// q = x@Wq.T (cols 0..63), k = x@Wk.T (cols 64..127), v = x@Wv.T (cols 128..255)
// M = B*N = 8192 rows, K = 128. Tile: 32 rows x 64 cols, full K in LDS.
// grid = (256, 4), block = 256.
__global__ __launch_bounds__(256) void proj_kernel(
    const float* __restrict__ x, const float* __restrict__ Wq,
    const float* __restrict__ Wk, const float* __restrict__ Wv,
    float* __restrict__ qws, float* __restrict__ kws, float* __restrict__ vws)
{
  __shared__ float xs[32 * 132];   // stride 132 = 4*33 (odd quad) -> conflict-free
  __shared__ float wsm[64 * 132];
  const int t = threadIdx.x;
  const int m0 = blockIdx.x * 32;
  const int nt = blockIdx.y;       // col tile 0..3

  // stage x tile: 32 x 128 = 1024 float4
  #pragma unroll
  for (int it = 0; it < 4; ++it) {
    int f = t + it * 256;
    int r = f >> 5, kq = f & 31;
    float4 v4 = *(const float4*)(x + (m0 + r) * 128 + kq * 4);
    *(float4*)(xs + r * 132 + kq * 4) = v4;
  }
  // stage W tile: 64 rows x 128 = 2048 float4
  const float* Wsrc = (nt == 0) ? Wq : (nt == 1) ? Wk : (Wv + (nt - 2) * 64 * 128);
  #pragma unroll
  for (int it = 0; it < 8; ++it) {
    int f = t + it * 256;
    int r = f >> 5, kq = f & 31;
    float4 v4 = *(const float4*)(Wsrc + r * 128 + kq * 4);
    *(float4*)(wsm + r * 132 + kq * 4) = v4;
  }
  __syncthreads();

  const int tm = t >> 4;   // rows tm, tm+16
  const int tn = t & 15;   // cols tn + {0,16,32,48}
  float acc[2][4];
  #pragma unroll
  for (int a = 0; a < 2; ++a)
    #pragma unroll
    for (int c = 0; c < 4; ++c) acc[a][c] = 0.f;

  for (int kq = 0; kq < 32; ++kq) {
    float4 xa = *(const float4*)(xs + tm * 132 + kq * 4);
    float4 xb = *(const float4*)(xs + (tm + 16) * 132 + kq * 4);
    #pragma unroll
    for (int c = 0; c < 4; ++c) {
      float4 wv = *(const float4*)(wsm + (tn + c * 16) * 132 + kq * 4);
      acc[0][c] += xa.x * wv.x + xa.y * wv.y + xa.z * wv.z + xa.w * wv.w;
      acc[1][c] += xb.x * wv.x + xb.y * wv.y + xb.z * wv.z + xb.w * wv.w;
    }
  }
  #pragma unroll
  for (int a = 0; a < 2; ++a) {
    int row = m0 + tm + a * 16;
    #pragma unroll
    for (int c = 0; c < 4; ++c) {
      int col = nt * 64 + tn + c * 16;   // block-uniform branch below
      float val = acc[a][c];
      if (col < 64)       qws[row * 64 + col] = val;
      else if (col < 128) kws[row * 64 + col - 64] = val;
      else                vws[row * 128 + col - 128] = val;
    }
  }
}

// ---------------- Kernel B: fused attention ----------------
// grid = 256 blocks = (b, i-tile of 32 rows); block = 256 threads.
// Thread role (main): i_loc = t>>3 (0..31), l = t&7.
// Per 32-wide j-tile: stage K/V/masks -> QK^T into packed rec -> mix+exp+PV.
#define IT 32
#define JT 32
#define KS_STRIDE 68    // 64+4: 68 mod 32 = 4 -> distinct bank quads across j
#define VS_STRIDE 516   // JT*16+4 per l
#define REC_STRIDE 260  // JT*8+4 per i; rec[i][j][8] = {attn0..3, m0..2, pad}

__global__ __launch_bounds__(256) void attn_kernel(
    const float* __restrict__ qws, const float* __restrict__ kws,
    const float* __restrict__ vws, const float* __restrict__ masks,
    const float* __restrict__ mask_proj, float* __restrict__ out)
{
  __shared__ float ks[JT * KS_STRIDE];
  __shared__ float vs[LL * VS_STRIDE];
  __shared__ float rec[IT * REC_STRIDE];

  const int t = threadIdx.x;
  const int b = blockIdx.x >> 5;
  const int i0 = (blockIdx.x & 31) * IT;
  const int i_loc = t >> 3;
  const int l = t & 7;
  const int jb = t & 7;   // attn-phase role

  // q register-resident: q[b][i0+i_loc][0..63]
  float4 qreg[16];
  {
    const float* qptr = qws + (b * NN + i0 + i_loc) * GD;
    #pragma unroll
    for (int q4 = 0; q4 < 16; ++q4) qreg[q4] = *(const float4*)(qptr + q4 * 4);
  }
  // mixing constants for this l: yc[m][g] = mask_proj[m, g*8+l]
  float yc[3][4];
  #pragma unroll
  for (int m = 0; m < 3; ++m)
    #pragma unroll
    for (int g = 0; g < 4; ++g) yc[m][g] = mask_proj[m * 32 + g * 8 + l];

  float4 acc0 = {0,0,0,0}, acc1 = {0,0,0,0}, acc2 = {0,0,0,0}, acc3 = {0,0,0,0};
  float denom = 0.f;

  const float* kbase0 = kws + (long)b * NN * GD;
  const float* vbase0 = vws + (long)b * NN * CC;
  const float* mbase0 = masks + (long)i0 * NN * 3;

  for (int jt = 0; jt < NN / JT; ++jt) {
    const int j0 = jt * JT;
    __syncthreads();  // protect LDS from previous tile's readers

    // ---- stage K (32x64), V (32x128), masks (32x32x3) ----
    {
      const float* kbase = kbase0 + j0 * GD;
      #pragma unroll
      for (int it2 = 0; it2 < 2; ++it2) {
        int f = t + it2 * 256;            // 512 float4
        int j = f >> 4, cq = f & 15;
        float4 v4 = *(const float4*)(kbase + j * GD + cq * 4);
        *(float4*)(ks + j * KS_STRIDE + cq * 4) = v4;
      }
      const float* vbase = vbase0 + j0 * CC;
      #pragma unroll
      for (int it2 = 0; it2 < 4; ++it2) {
        int f = t + it2 * 256;            // 1024 float4
        int j = f >> 5, cq = f & 31;
        float4 v4 = *(const float4*)(vbase + j * CC + cq * 4);
        int ll2 = cq >> 2, dq = cq & 3;
        *(float4*)(vs + ll2 * VS_STRIDE + j * 16 + dq * 4) = v4;
      }
      const float* mbase = mbase0 + j0 * 3;
      #pragma unroll
      for (int it2 = 0; it2 < 12; ++it2) {
        int f = t + it2 * 256;            // 3072 floats
        int ii = f / 96;
        int rrem = f - ii * 96;           // j*3+m within row
        int jj = rrem / 3;
        int m = rrem - jj * 3;
        rec[ii * REC_STRIDE + jj * 8 + 4 + m] = mbase[ii * NN * 3 + rrem];
      }
    }
    __syncthreads();

    // ---- QK^T phase: thread (i_loc, jb) computes attn[g] for j = jb+8*jj ----
    #pragma unroll
    for (int jj = 0; jj < 4; ++jj) {
      int j = jb + jj * 8;
      float4 av;
      float* ap = (float*)&av;
      #pragma unroll
      for (int g = 0; g < 4; ++g) {
        const float* kp = ks + j * KS_STRIDE + g * 16;
        float4 k0 = *(const float4*)(kp);
        float4 k1 = *(const float4*)(kp + 4);
        float4 k2 = *(const float4*)(kp + 8);
        float4 k3 = *(const float4*)(kp + 12);
        float4 qa = qreg[g*4+0], qb = qreg[g*4+1], qc = qreg[g*4+2], qd = qreg[g*4+3];
        float s = qa.x*k0.x + qa.y*k0.y + qa.z*k0.z + qa.w*k0.w
                + qb.x*k1.x + qb.y*k1.y + qb.z*k1.z + qb.w*k1.w
                + qc.x*k2.x + qc.y*k2.y + qc.z*k2.z + qc.w*k2.w
                + qd.x*k3.x + qd.y*k3.y + qd.z*k3.z + qd.w*k3.w;
        ap[g] = s;
      }
      *(float4*)(rec + i_loc * REC_STRIDE + j * 8) = av;
    }
    __syncthreads();

    // ---- mix + exp + PV phase: thread (i_loc, l) ----
    {
      const float* rbase = rec + i_loc * REC_STRIDE;
      const float* vbase = vs + l * VS_STRIDE;
      #pragma unroll 8
      for (int j = 0; j < JT; ++j) {
        float4 a  = *(const float4*)(rbase + j * 8);
        float4 mk = *(const float4*)(rbase + j * 8 + 4);  // masks in x,y,z
        float w0 = mk.x*yc[0][0] + mk.y*yc[1][0] + mk.z*yc[2][0];
        float w1 = mk.x*yc[0][1] + mk.y*yc[1][1] + mk.z*yc[2][1];
        float w2 = mk.x*yc[0][2] + mk.y*yc[1][2] + mk.z*yc[2][2];
        float w3 = mk.x*yc[0][3] + mk.y*yc[1][3] + mk.z*yc[2][3];
        float s = a.x*w0 + a.y*w1 + a.z*w2 + a.w*w3;
        float e = __expf(s);
        denom += e;
        const float* vp = vbase + j * 16;
        float4 v0 = *(const float4*)(vp);
        float4 v1 = *(const float4*)(vp + 4);
        float4 v2 = *(const float4*)(vp + 8);
        float4 v3 = *(const float4*)(vp + 12);
        acc0.x += e*v0.x; acc0.y += e*v0.y; acc0.z += e*v0.z; acc0.w += e*v0.w;
        acc1.x += e*v1.x; acc1.y += e*v1.y; acc1.z += e*v1.z; acc1.w += e*v1.w;
        acc2.x += e*v2.x; acc2.y += e*v2.y; acc2.z += e*v2.z; acc2.w += e*v2.w;
        acc3.x += e*v3.x; acc3.y += e*v3.y; acc3.z += e*v3.z; acc3.w += e*v3.w;
      }
    }
  }

  // epilogue: out[b, i, l*16+d] = acc/denom
  float inv = 1.0f / denom;
  float* op = out + ((long)(b * NN + i0 + i_loc)) * CC + l * 16;
  acc0.x *= inv; acc0.y *= inv; acc0.z *= inv; acc0.w *= inv;
  acc1.x *= inv; acc1.y *= inv; acc1.z *= inv; acc1.w *= inv;
  acc2.x *= inv; acc2.y *= inv; acc2.z *= inv; acc2.w *= inv;
  acc3.x *= inv; acc3.y *= inv; acc3.z *= inv; acc3.w *= inv;
  *(float4*)(op)      = acc0;
  *(float4*)(op + 4)  = acc1;
  *(float4*)(op + 8)  = acc2;
  *(float4*)(op + 12) = acc3;
}

extern "C" void kernel_launch(void* const* d_in, const int* in_sizes, int n_in,
                              void* d_out, int out_size, void* d_ws, size_t ws_size,
                              hipStream_t stream) {
  const float* x         = (const float*)d_in[0];
  const float* masks     = (const float*)d_in[1];
  const float* Wq        = (const float*)d_in[2];
  const float* Wk        = (const float*)d_in[3];
  const float* Wv        = (const float*)d_in[4];
  const float* mask_proj = (const float*)d_in[5];
  float* out = (float*)d_out;

  // workspace: q (B*N*64), k (B*N*64), v (B*N*128) fp32 = 8 MB total
  float* qws = (float*)d_ws;
  float* kws = qws + (size_t)BB * NN * GD;
  float* vws = kws + (size_t)BB * NN * GD;

  dim3 gA(256, 4);
  proj_kernel<<<gA, 256, 0, stream>>>(x, Wq, Wk, Wv, qws, kws, vws);

  dim3 gB(BB * (NN / IT));   // 256 blocks
  attn_kernel<<<gB, 256, 0, stream>>>(qws, kws, vws, masks, mask_proj, out);
}

// Round 2
// 213.657 us; speedup vs baseline: 1.4800x; 1.4800x over previous
//
#include <hip/hip_runtime.h>

#define BB 8
#define NN 1024
#define CC 128
#define GG 4
#define LL 8
#define HD 16
#define GD 64   // GG*HD

// ---------------- Kernel A: projections q/k/v ----------------
__global__ __launch_bounds__(256) void proj_kernel(
    const float* __restrict__ x, const float* __restrict__ Wq,
    const float* __restrict__ Wk, const float* __restrict__ Wv,
    float* __restrict__ qws, float* __restrict__ kws, float* __restrict__ vws)
{
  __shared__ float xs[32 * 132];
  __shared__ float wsm[64 * 132];
  const int t = threadIdx.x;
  const int m0 = blockIdx.x * 32;
  const int nt = blockIdx.y;       // col tile 0..3

  #pragma unroll
  for (int it = 0; it < 4; ++it) {
    int f = t + it * 256;
    int r = f >> 5, kq = f & 31;
    float4 v4 = *(const float4*)(x + (m0 + r) * 128 + kq * 4);
    *(float4*)(xs + r * 132 + kq * 4) = v4;
  }
  const float* Wsrc = (nt == 0) ? Wq : (nt == 1) ? Wk : (Wv + (nt - 2) * 64 * 128);
  #pragma unroll
  for (int it = 0; it < 8; ++it) {
    int f = t + it * 256;
    int r = f >> 5, kq = f & 31;
    float4 v4 = *(const float4*)(Wsrc + r * 128 + kq * 4);
    *(float4*)(wsm + r * 132 + kq * 4) = v4;
  }
  __syncthreads();

  const int tm = t >> 4;
  const int tn = t & 15;
  float acc[2][4];
  #pragma unroll
  for (int a = 0; a < 2; ++a)
    #pragma unroll
    for (int c = 0; c < 4; ++c) acc[a][c] = 0.f;

  for (int kq = 0; kq < 32; ++kq) {
    float4 xa = *(const float4*)(xs + tm * 132 + kq * 4);
    float4 xb = *(const float4*)(xs + (tm + 16) * 132 + kq * 4);
    #pragma unroll
    for (int c = 0; c < 4; ++c) {
      float4 wv = *(const float4*)(wsm + (tn + c * 16) * 132 + kq * 4);
      acc[0][c] += xa.x * wv.x + xa.y * wv.y + xa.z * wv.z + xa.w * wv.w;
      acc[1][c] += xb.x * wv.x + xb.y * wv.y + xb.z * wv.z + xb.w * wv.w;
    }
  }
  #pragma unroll
  for (int a = 0; a < 2; ++a) {
    int row = m0 + tm + a * 16;
    #pragma unroll
    for (int c = 0; c < 4; ++c) {
      int col = nt * 64 + tn + c * 16;
      float val = acc[a][c];
      if (col < 64)       qws[row * 64 + col] = val;
      else if (col < 128) kws[row * 64 + col - 64] = val;
      else                vws[row * 128 + col - 128] = val;
    }
  }
}

// ---------------- Kernel B: fused attention (j-split partials) ----------------
// grid = 1024 blocks = (b, 32-row i-tile, j-split s of 4); block = 256 threads.
// Each block covers j in [s*256, (s+1)*256) as 16 tiles of JT=16, accumulating
// partial (sum e*v, sum e) -> workspace; reduce_kernel combines.
#define IT 32
#define JT 16
#define SPLIT 4
#define JSPAN (NN / SPLIT)          // 256 keys per block
#define KS_STRIDE 68                // 16 rows x (64+4)
#define VS_STRIDE 260               // 8 l x (16*16+4)
#define REC_STRIDE 132              // 32 i x (16*8+4); rec[i][j][8]={attn0..3,m0..2,pad}

__global__ __launch_bounds__(256) void attn_kernel(
    const float* __restrict__ qws, const float* __restrict__ kws,
    const float* __restrict__ vws, const float* __restrict__ masks,
    const float* __restrict__ mask_proj,
    float* __restrict__ pnum, float* __restrict__ pden)
{
  __shared__ float ks[JT * KS_STRIDE];
  __shared__ float vs[LL * VS_STRIDE];
  __shared__ float rec[IT * REC_STRIDE];

  const int t = threadIdx.x;
  const int s  = blockIdx.x & 3;
  const int it = (blockIdx.x >> 2) & 31;
  const int b  = blockIdx.x >> 7;
  const int i0 = it * IT;
  const int jbase = s * JSPAN;

  const int i_loc = t >> 3;   // 0..31 (PV+QK row)
  const int l  = t & 7;       // PV local head
  const int jb = t & 7;       // QK j sub-index

  // q register-resident
  float4 qreg[16];
  {
    const float* qptr = qws + (b * NN + i0 + i_loc) * GD;
    #pragma unroll
    for (int q4 = 0; q4 < 16; ++q4) qreg[q4] = *(const float4*)(qptr + q4 * 4);
  }
  float yc[3][4];
  #pragma unroll
  for (int m = 0; m < 3; ++m)
    #pragma unroll
    for (int g = 0; g < 4; ++g) yc[m][g] = mask_proj[m * 32 + g * 8 + l];

  float4 acc0 = {0,0,0,0}, acc1 = {0,0,0,0}, acc2 = {0,0,0,0}, acc3 = {0,0,0,0};
  float denom = 0.f;

  const float* kbase0 = kws + (long)b * NN * GD;
  const float* vbase0 = vws + (long)b * NN * CC;
  const float* mbase0 = masks + (long)i0 * NN * 3;

  for (int jt = 0; jt < JSPAN / JT; ++jt) {
    const int j0 = jbase + jt * JT;
    __syncthreads();  // protect LDS from previous tile's readers

    // ---- stage K (16x64), V (16x128), masks (32x16x3) ----
    {
      const float* kbase = kbase0 + j0 * GD;
      {
        int f = t;                        // 256 float4
        int j = f >> 4, cq = f & 15;
        float4 v4 = *(const float4*)(kbase + j * GD + cq * 4);
        *(float4*)(ks + j * KS_STRIDE + cq * 4) = v4;
      }
      const float* vbase = vbase0 + j0 * CC;
      #pragma unroll
      for (int it2 = 0; it2 < 2; ++it2) {
        int f = t + it2 * 256;            // 512 float4
        int j = f >> 5, cq = f & 31;
        float4 v4 = *(const float4*)(vbase + j * CC + cq * 4);
        int ll2 = cq >> 2, dq = cq & 3;
        *(float4*)(vs + ll2 * VS_STRIDE + j * 16 + dq * 4) = v4;
      }
      const float* mbase = mbase0 + j0 * 3;
      #pragma unroll
      for (int it2 = 0; it2 < 6; ++it2) {
        int f = t + it2 * 256;            // 1536 floats: 32 i x (16 j x 3 m)
        int ii = f / 48;
        int rrem = f - ii * 48;           // jj*3+m
        int jj = rrem / 3;
        int m = rrem - jj * 3;
        rec[ii * REC_STRIDE + jj * 8 + 4 + m] = mbase[ii * NN * 3 + rrem];
      }
    }
    __syncthreads();

    // ---- QK^T: thread (i_loc, jb) -> attn[g] for j = jb, jb+8 ----
    #pragma unroll
    for (int jj = 0; jj < 2; ++jj) {
      int j = jb + jj * 8;
      float4 av;
      float* ap = (float*)&av;
      #pragma unroll
      for (int g = 0; g < 4; ++g) {
        const float* kp = ks + j * KS_STRIDE + g * 16;
        float4 k0 = *(const float4*)(kp);
        float4 k1 = *(const float4*)(kp + 4);
        float4 k2 = *(const float4*)(kp + 8);
        float4 k3 = *(const float4*)(kp + 12);
        float4 qa = qreg[g*4+0], qb = qreg[g*4+1], qc = qreg[g*4+2], qd = qreg[g*4+3];
        float sd = qa.x*k0.x + qa.y*k0.y + qa.z*k0.z + qa.w*k0.w
                 + qb.x*k1.x + qb.y*k1.y + qb.z*k1.z + qb.w*k1.w
                 + qc.x*k2.x + qc.y*k2.y + qc.z*k2.z + qc.w*k2.w
                 + qd.x*k3.x + qd.y*k3.y + qd.z*k3.z + qd.w*k3.w;
        ap[g] = sd;
      }
      *(float4*)(rec + i_loc * REC_STRIDE + j * 8) = av;
    }
    __syncthreads();

    // ---- mix + exp + PV: thread (i_loc, l) ----
    {
      const float* rbase = rec + i_loc * REC_STRIDE;
      const float* vbase = vs + l * VS_STRIDE;
      #pragma unroll
      for (int j = 0; j < JT; ++j) {
        float4 a  = *(const float4*)(rbase + j * 8);
        float4 mk = *(const float4*)(rbase + j * 8 + 4);
        float w0 = mk.x*yc[0][0] + mk.y*yc[1][0] + mk.z*yc[2][0];
        float w1 = mk.x*yc[0][1] + mk.y*yc[1][1] + mk.z*yc[2][1];
        float w2 = mk.x*yc[0][2] + mk.y*yc[1][2] + mk.z*yc[2][2];
        float w3 = mk.x*yc[0][3] + mk.y*yc[1][3] + mk.z*yc[2][3];
        float sc = a.x*w0 + a.y*w1 + a.z*w2 + a.w*w3;
        float e = __expf(sc);
        denom += e;
        const float* vp = vbase + j * 16;
        float4 v0 = *(const float4*)(vp);
        float4 v1 = *(const float4*)(vp + 4);
        float4 v2 = *(const float4*)(vp + 8);
        float4 v3 = *(const float4*)(vp + 12);
        acc0.x += e*v0.x; acc0.y += e*v0.y; acc0.z += e*v0.z; acc0.w += e*v0.w;
        acc1.x += e*v1.x; acc1.y += e*v1.y; acc1.z += e*v1.z; acc1.w += e*v1.w;
        acc2.x += e*v2.x; acc2.y += e*v2.y; acc2.z += e*v2.z; acc2.w += e*v2.w;
        acc3.x += e*v3.x; acc3.y += e*v3.y; acc3.z += e*v3.z; acc3.w += e*v3.w;
      }
    }
  }

  // epilogue: partial numerator + denominator to workspace
  long row = (long)s * BB * NN + b * NN + i0 + i_loc;
  float* np = pnum + row * CC + l * 16;
  *(float4*)(np)      = acc0;
  *(float4*)(np + 4)  = acc1;
  *(float4*)(np + 8)  = acc2;
  *(float4*)(np + 12) = acc3;
  pden[row * LL + l] = denom;
}

// ---------------- Kernel C: combine partials ----------------
__global__ __launch_bounds__(256) void reduce_kernel(
    const float* __restrict__ pnum, const float* __restrict__ pden,
    float* __restrict__ out)
{
  int idx = blockIdx.x * 256 + threadIdx.x;       // 0 .. 8192*128
  int bi = idx >> 7;
  int l  = (idx & 127) >> 4;
  float num = 0.f, den = 0.f;
  #pragma unroll
  for (int s = 0; s < SPLIT; ++s) {
    num += pnum[(long)s * BB * NN * CC + idx];
    den += pden[(long)s * BB * NN * LL + bi * LL + l];
  }
  out[idx] = num / den;
}

extern "C" void kernel_launch(void* const* d_in, const int* in_sizes, int n_in,
                              void* d_out, int out_size, void* d_ws, size_t ws_size,
                              hipStream_t stream) {
  const float* x         = (const float*)d_in[0];
  const float* masks     = (const float*)d_in[1];
  const float* Wq        = (const float*)d_in[2];
  const float* Wk        = (const float*)d_in[3];
  const float* Wv        = (const float*)d_in[4];
  const float* mask_proj = (const float*)d_in[5];
  float* out = (float*)d_out;

  // ws layout (floats): q 512K | k 512K | v 1M | pnum 4M | pden 256K  = 25.2 MB
  float* qws  = (float*)d_ws;
  float* kws  = qws + (size_t)BB * NN * GD;
  float* vws  = kws + (size_t)BB * NN * GD;
  float* pnum = vws + (size_t)BB * NN * CC;
  float* pden = pnum + (size_t)SPLIT * BB * NN * CC;

  dim3 gA(256, 4);
  proj_kernel<<<gA, 256, 0, stream>>>(x, Wq, Wk, Wv, qws, kws, vws);

  dim3 gB(BB * (NN / IT) * SPLIT);   // 1024 blocks
  attn_kernel<<<gB, 256, 0, stream>>>(qws, kws, vws, masks, mask_proj, pnum, pden);

  dim3 gC((BB * NN * CC) / 256);     // 4096 blocks
  reduce_kernel<<<gC, 256, 0, stream>>>(pnum, pden, out);
}

// Round 3
// 182.887 us; speedup vs baseline: 1.7290x; 1.1682x over previous
//
#include <hip/hip_runtime.h>

#define BB 8
#define NN 1024
#define CC 128
#define GG 4
#define LL 8
#define GD 64   // GG*16

typedef __attribute__((ext_vector_type(8))) short short8;
typedef __attribute__((ext_vector_type(4))) short short4v;
typedef __attribute__((ext_vector_type(4))) float floatx4;

__device__ __forceinline__ short f2b(float f) {
  union { float f; unsigned u; } c; c.f = f;
  unsigned u = c.u;
  return (short)((u + 0x7FFFu + ((u >> 16) & 1u)) >> 16);   // RNE fp32->bf16
}

// ---------------- Kernel A: projections q/k/v (v written transposed) --------
// qws/kws: [B*N][64] row-major. vtg: [B][128 c][1024 tok] (transposed).
__global__ __launch_bounds__(256) void proj_kernel(
    const float* __restrict__ x, const float* __restrict__ Wq,
    const float* __restrict__ Wk, const float* __restrict__ Wv,
    float* __restrict__ qws, float* __restrict__ kws, float* __restrict__ vtg)
{
  __shared__ float xs[32 * 132];
  __shared__ float wsm[64 * 132];
  const int t = threadIdx.x;
  const int m0 = blockIdx.x * 32;

  #pragma unroll
  for (int it = 0; it < 4; ++it) {
    int f = t + it * 256;
    int r = f >> 5, kq = f & 31;
    *(float4*)(xs + r * 132 + kq * 4) = *(const float4*)(x + (m0 + r) * 128 + kq * 4);
  }

  const int tm = t >> 4;
  const int tn = t & 15;

  for (int nt = 0; nt < 4; ++nt) {
    __syncthreads();   // wsm safe to overwrite (also covers xs on first pass)
    const float* Wsrc = (nt == 0) ? Wq : (nt == 1) ? Wk : (Wv + (nt - 2) * 64 * 128);
    #pragma unroll
    for (int it = 0; it < 8; ++it) {
      int f = t + it * 256;
      int r = f >> 5, kq = f & 31;
      *(float4*)(wsm + r * 132 + kq * 4) = *(const float4*)(Wsrc + r * 128 + kq * 4);
    }
    __syncthreads();

    float acc[2][4] = {};
    for (int kq = 0; kq < 32; ++kq) {
      float4 xa = *(const float4*)(xs + tm * 132 + kq * 4);
      float4 xb = *(const float4*)(xs + (tm + 16) * 132 + kq * 4);
      #pragma unroll
      for (int c = 0; c < 4; ++c) {
        float4 wv = *(const float4*)(wsm + (tn + c * 16) * 132 + kq * 4);
        acc[0][c] += xa.x*wv.x + xa.y*wv.y + xa.z*wv.z + xa.w*wv.w;
        acc[1][c] += xb.x*wv.x + xb.y*wv.y + xb.z*wv.z + xb.w*wv.w;
      }
    }
    #pragma unroll
    for (int a = 0; a < 2; ++a) {
      int row = m0 + tm + a * 16;
      #pragma unroll
      for (int c = 0; c < 4; ++c) {
        int col = tn + c * 16;
        float val = acc[a][c];
        if (nt == 0)      qws[row * 64 + col] = val;
        else if (nt == 1) kws[row * 64 + col] = val;
        else {
          int b2 = row >> 10, tok = row & 1023;
          int cv = (nt - 2) * 64 + col;
          vtg[((long)b2 * CC + cv) * NN + tok] = val;
        }
      }
    }
  }
}

// ---------------- Kernel B: MFMA fused attention ----------------
// grid = 1024: sp = bx&1 (j-split), itile = (bx>>1)&63, b = bx>>7.
// Block 256 thr = 4 waves. Per 32-j tile:
//  [bar] stage K(bf16), Vt(bf16), masks(fp32) [bar]
//  QK: wave g -> 2x mfma_16x16x32_bf16 (K zero-padded 16->32) -> arec (C-layout)
//  [bar] mix+exp (thread=(jh2,i,l)) fp32 -> P bf16 into pbuf (A-layout) [bar]
//  PV: wave w, l in {2w,2w+1}: mfma(P, Vt) accumulate.
#define IT 16
#define JT 32
#define SPLIT 2
#define JSPAN (NN / SPLIT)
#define NTL (JSPAN / JT)   // 16 tiles

#define KSP 72    // bf16 stride per j-row of ks   (16B-aligned rows)
#define VTP 32    // bf16 stride per c-row of vt
#define MRP 132   // dword stride per i-row of mrec (33 chunks, odd -> spread)
#define ARP 72    // dword stride per j-row of arec (18 chunks)
#define PIP 40    // bf16 stride per i-row of pbuf  (5 chunks, odd)
#define PLP 648   // bf16 stride per l-plane of pbuf (81 chunks, odd)

__global__ __launch_bounds__(256) void attn_kernel(
    const float* __restrict__ qws, const float* __restrict__ kws,
    const float* __restrict__ vtg, const float* __restrict__ masks,
    const float* __restrict__ mask_proj,
    float* __restrict__ pnum, float* __restrict__ pden2)
{
  __shared__ short ks[JT * KSP];      // 4608 B
  __shared__ short vt[CC * VTP];      // 8192 B
  __shared__ float mrec[IT * MRP];    // 8448 B
  __shared__ float arec[JT * ARP];    // 9216 B
  __shared__ short pbuf[LL * PLP];    // 10368 B   (total 40832 B)

  const int t = threadIdx.x;
  const int sp = blockIdx.x & 1;
  const int itile = (blockIdx.x >> 1) & 63;
  const int b = blockIdx.x >> 7;
  const int i0 = itile * IT;
  const int jbase = sp * JSPAN;

  const int w = t >> 6;          // wave id = g (QK) ; l-pair (PV)
  const int lane = t & 63;
  const int ln = lane & 15;
  const int hq = lane >> 4;      // 0..3

  // phase-3 roles
  const int jh2 = t >> 7;        // j-half 0/1
  const int il = (t >> 3) & 15;  // i 0..15
  const int l = t & 7;

  // Q A-fragment, register resident (wave w handles g = w). K padded 16->32: hq>=2 zero.
  short8 qf;
  {
    union { short s[8]; short8 v; } qq;
    #pragma unroll
    for (int z = 0; z < 8; ++z) qq.s[z] = 0;
    if (hq < 2) {
      const float* qp = qws + ((long)(b * NN + i0 + ln)) * GD + w * 16 + hq * 8;
      float4 a = *(const float4*)qp;
      float4 bq = *(const float4*)(qp + 4);
      qq.s[0]=f2b(a.x); qq.s[1]=f2b(a.y); qq.s[2]=f2b(a.z); qq.s[3]=f2b(a.w);
      qq.s[4]=f2b(bq.x); qq.s[5]=f2b(bq.y); qq.s[6]=f2b(bq.z); qq.s[7]=f2b(bq.w);
    }
    qf = qq.v;
  }

  float yc[3][4];
  #pragma unroll
  for (int m = 0; m < 3; ++m)
    #pragma unroll
    for (int g2 = 0; g2 < 4; ++g2) yc[m][g2] = mask_proj[m * 32 + g2 * 8 + l];

  const floatx4 zf = {0.f, 0.f, 0.f, 0.f};
  floatx4 pvacc[2] = {zf, zf};
  float denom = 0.f;

  const float* kbase0 = kws + (long)b * NN * GD;
  const float* vbase0 = vtg + (long)b * CC * NN;
  const long mbase0 = (long)i0 * NN * 3;

  for (int jt = 0; jt < NTL; ++jt) {
    const int j0 = jbase + jt * JT;
    __syncthreads();   // A: prev tile's readers of ks/vt/mrec/pbuf done

    // ---- stage K: 32 j x 64 d fp32 -> bf16 ----
    {
      int jloc = t >> 3, dg = t & 7;
      const float* src = kbase0 + (long)(j0 + jloc) * GD + dg * 8;
      float4 u0 = *(const float4*)(src);
      float4 u1 = *(const float4*)(src + 4);
      union { short s[8]; short8 v; } kp;
      kp.s[0]=f2b(u0.x); kp.s[1]=f2b(u0.y); kp.s[2]=f2b(u0.z); kp.s[3]=f2b(u0.w);
      kp.s[4]=f2b(u1.x); kp.s[5]=f2b(u1.y); kp.s[6]=f2b(u1.z); kp.s[7]=f2b(u1.w);
      *(short8*)(ks + jloc * KSP + dg * 8) = kp.v;
    }
    // ---- stage V (transposed source): 128 c x 32 j fp32 -> bf16 ----
    #pragma unroll
    for (int it2 = 0; it2 < 4; ++it2) {
      int f = t + it2 * 256;
      int c = f >> 3, jq = f & 7;
      float4 u = *(const float4*)(vbase0 + (long)c * NN + j0 + jq * 4);
      union { short s[4]; short4v v; } vp;
      vp.s[0]=f2b(u.x); vp.s[1]=f2b(u.y); vp.s[2]=f2b(u.z); vp.s[3]=f2b(u.w);
      *(short4v*)(vt + c * VTP + jq * 4) = vp.v;
    }
    // ---- stage masks: 16 i x 32 j x 3 fp32 ----
    #pragma unroll
    for (int it2 = 0; it2 < 6; ++it2) {
      int f = t + it2 * 256;               // 1536 total
      int ii = f / 96;
      int rr = f - ii * 96;                // jj*3 + m
      int jj = rr / 3;
      int m = rr - jj * 3;
      mrec[ii * MRP + jj * 4 + m] = masks[mbase0 + (long)ii * 3072 + (long)j0 * 3 + rr];
    }
    __syncthreads();   // B: tiles staged

    // ---- QK MFMA: wave g = w ----
    #pragma unroll
    for (int jh = 0; jh < 2; ++jh) {
      union { short s[8]; short8 v; } kk;
      #pragma unroll
      for (int z = 0; z < 8; ++z) kk.s[z] = 0;
      if (hq < 2)
        kk.v = *(const short8*)(ks + (jh * 16 + ln) * KSP + w * 16 + hq * 8);
      floatx4 at = __builtin_amdgcn_mfma_f32_16x16x32_bf16(qf, kk.v, zf, 0, 0, 0);
      // C-layout: col(j)=lane&15, row(i)=(lane>>4)*4+reg
      float* ab = arec + (jh * 16 + ln) * ARP + w;
      #pragma unroll
      for (int reg = 0; reg < 4; ++reg)
        ab[(hq * 4 + reg) * 4] = at[reg];
    }
    __syncthreads();   // C: arec ready

    // ---- mix + exp -> P (bf16, A-layout) ----
    {
      union { short s[8]; short8 v; } pj;
      #pragma unroll
      for (int jp = 0; jp < 16; ++jp) {
        int j = jh2 * 16 + jp;
        floatx4 a4 = *(const floatx4*)(arec + j * ARP + il * 4);
        float4 mk = *(const float4*)(mrec + il * MRP + j * 4);
        float w0 = mk.x*yc[0][0] + mk.y*yc[1][0] + mk.z*yc[2][0];
        float w1 = mk.x*yc[0][1] + mk.y*yc[1][1] + mk.z*yc[2][1];
        float w2 = mk.x*yc[0][2] + mk.y*yc[1][2] + mk.z*yc[2][2];
        float w3 = mk.x*yc[0][3] + mk.y*yc[1][3] + mk.z*yc[2][3];
        float sc = a4[0]*w0 + a4[1]*w1 + a4[2]*w2 + a4[3]*w3;
        float e = __expf(sc);
        denom += e;
        pj.s[jp & 7] = f2b(e);
        if ((jp & 7) == 7)
          *(short8*)(pbuf + l * PLP + il * PIP + jh2 * 16 + (jp >> 3) * 8) = pj.v;
      }
    }
    __syncthreads();   // D: pbuf ready

    // ---- PV MFMA: wave w handles l = 2w, 2w+1 ----
    #pragma unroll
    for (int li = 0; li < 2; ++li) {
      int l2 = 2 * w + li;
      short8 pf = *(const short8*)(pbuf + l2 * PLP + ln * PIP + hq * 8);
      short8 vf = *(const short8*)(vt + (l2 * 16 + ln) * VTP + hq * 8);
      pvacc[li] = __builtin_amdgcn_mfma_f32_16x16x32_bf16(pf, vf, pvacc[li], 0, 0, 0);
    }
  }

  // ---- epilogue: partials ----
  #pragma unroll
  for (int li = 0; li < 2; ++li) {
    int l2 = 2 * w + li;
    #pragma unroll
    for (int reg = 0; reg < 4; ++reg) {
      long row = ((long)(sp * BB + b)) * NN + i0 + hq * 4 + reg;
      pnum[row * CC + l2 * 16 + ln] = pvacc[li][reg];
    }
  }
  pden2[(((long)sp * BB + b) * NN + i0 + il) * 16 + l * 2 + jh2] = denom;
}

// ---------------- Kernel C: combine partials ----------------
__global__ __launch_bounds__(256) void reduce_kernel(
    const float* __restrict__ pnum, const float* __restrict__ pden2,
    float* __restrict__ out)
{
  int e4 = blockIdx.x * 256 + threadIdx.x;   // float4 index, 0..262143
  int bi = e4 >> 5;                          // global token 0..8191
  int c4 = e4 & 31;
  int l = c4 >> 2;
  const float4* p4 = (const float4*)pnum;
  float4 n0 = p4[e4];
  float4 n1 = p4[e4 + (BB * NN * CC / 4)];
  float den = 0.f;
  #pragma unroll
  for (int s = 0; s < SPLIT; ++s)
    #pragma unroll
    for (int h = 0; h < 2; ++h)
      den += pden2[((long)s * BB * NN + bi) * 16 + l * 2 + h];
  float inv = 1.0f / den;
  float4 o;
  o.x = (n0.x + n1.x) * inv;
  o.y = (n0.y + n1.y) * inv;
  o.z = (n0.z + n1.z) * inv;
  o.w = (n0.w + n1.w) * inv;
  ((float4*)out)[e4] = o;
}

extern "C" void kernel_launch(void* const* d_in, const int* in_sizes, int n_in,
                              void* d_out, int out_size, void* d_ws, size_t ws_size,
                              hipStream_t stream) {
  const float* x         = (const float*)d_in[0];
  const float* masks     = (const float*)d_in[1];
  const float* Wq        = (const float*)d_in[2];
  const float* Wk        = (const float*)d_in[3];
  const float* Wv        = (const float*)d_in[4];
  const float* mask_proj = (const float*)d_in[5];
  float* out = (float*)d_out;

  // ws (floats): qws 512K | kws 512K | vtg 1M | pnum 2M | pden2 256K = 17.8 MB
  float* qws   = (float*)d_ws;
  float* kws   = qws + (size_t)BB * NN * GD;
  float* vtg   = kws + (size_t)BB * NN * GD;
  float* pnum  = vtg + (size_t)BB * NN * CC;
  float* pden2 = pnum + (size_t)SPLIT * BB * NN * CC;

  proj_kernel<<<256, 256, 0, stream>>>(x, Wq, Wk, Wv, qws, kws, vtg);
  attn_kernel<<<BB * (NN / IT) * SPLIT, 256, 0, stream>>>(qws, kws, vtg, masks,
                                                          mask_proj, pnum, pden2);
  reduce_kernel<<<(BB * NN * CC / 4) / 256, 256, 0, stream>>>(pnum, pden2, out);
}

// Round 5
// 156.390 us; speedup vs baseline: 2.0219x; 1.1694x over previous
//
#include <hip/hip_runtime.h>

#define BB 8
#define NN 1024
#define CC 128
#define GG 4
#define LL 8
#define GD 64

typedef __attribute__((ext_vector_type(8))) short short8;
typedef __attribute__((ext_vector_type(4))) float floatx4;

__device__ __forceinline__ short f2b(float f) {
  union { float f; unsigned u; } c; c.f = f;
  unsigned u = c.u;
  return (short)((u + 0x7FFFu + ((u >> 16) & 1u)) >> 16);   // RNE fp32->bf16
}
__device__ __forceinline__ float b2f(short s) {
  union { unsigned u; float f; } c; c.u = ((unsigned)(unsigned short)s) << 16;
  return c.f;
}

// ---------------- Kernel 0: pack masks [i][j][3] -> [i][j][4] fp32 ----------
__global__ __launch_bounds__(256) void mpack_kernel(
    const float* __restrict__ masks, float* __restrict__ mpk)
{
  int e = blockIdx.x * 256 + threadIdx.x;     // 0..1M-1 = (i,j)
  const float* s = masks + (long)e * 3;
  float4 o; o.x = s[0]; o.y = s[1]; o.z = s[2]; o.w = 0.f;
  ((float4*)mpk)[e] = o;
}

// ---------------- Kernel A: projections -> bf16 (V transposed) ----------
// nt 0: q rows [8192][64]; nt 1: k rows; nt 2,3: v cols -> vtb [b][128][1024].
// For nt>=2 the (tm,tn) roles swap so vtb stores are tok-contiguous.
__global__ __launch_bounds__(256) void proj_kernel(
    const float* __restrict__ x, const float* __restrict__ Wq,
    const float* __restrict__ Wk, const float* __restrict__ Wv,
    short* __restrict__ qb, short* __restrict__ kb, short* __restrict__ vtb)
{
  __shared__ float xs[32 * 132];
  __shared__ float wsm[64 * 132];
  const int t = threadIdx.x;
  const int m0 = blockIdx.x * 32;
  const int nt = blockIdx.y;

  #pragma unroll
  for (int it = 0; it < 4; ++it) {
    int f = t + it * 256;
    int r = f >> 5, kq = f & 31;
    *(float4*)(xs + r * 132 + kq * 4) = *(const float4*)(x + (m0 + r) * 128 + kq * 4);
  }
  const float* Wsrc = (nt == 0) ? Wq : (nt == 1) ? Wk : (Wv + (nt - 2) * 64 * 128);
  #pragma unroll
  for (int it = 0; it < 8; ++it) {
    int f = t + it * 256;
    int r = f >> 5, kq = f & 31;
    *(float4*)(wsm + r * 132 + kq * 4) = *(const float4*)(Wsrc + r * 128 + kq * 4);
  }
  __syncthreads();

  const int tm = (nt < 2) ? (t >> 4) : (t & 15);
  const int tn = (nt < 2) ? (t & 15) : (t >> 4);
  float acc[2][4] = {};
  for (int kq = 0; kq < 32; ++kq) {
    float4 xa = *(const float4*)(xs + tm * 132 + kq * 4);
    float4 xb = *(const float4*)(xs + (tm + 16) * 132 + kq * 4);
    #pragma unroll
    for (int c = 0; c < 4; ++c) {
      float4 wv = *(const float4*)(wsm + (tn + c * 16) * 132 + kq * 4);
      acc[0][c] += xa.x*wv.x + xa.y*wv.y + xa.z*wv.z + xa.w*wv.w;
      acc[1][c] += xb.x*wv.x + xb.y*wv.y + xb.z*wv.z + xb.w*wv.w;
    }
  }
  #pragma unroll
  for (int a = 0; a < 2; ++a) {
    int row = m0 + tm + a * 16;
    #pragma unroll
    for (int c = 0; c < 4; ++c) {
      short vb = f2b(acc[a][c]);
      int col = tn + c * 16;
      if (nt == 0)      qb[row * 64 + col] = vb;
      else if (nt == 1) kb[row * 64 + col] = vb;
      else {
        int b2 = row >> 10, tok = row & 1023;
        int cv = (nt - 2) * 64 + col;
        vtb[((long)b2 * CC + cv) * NN + tok] = vb;   // lanes tm = consecutive tok
      }
    }
  }
}

// ---------------- Kernel B: MFMA fused attention, JT=64 ----------------
// grid 1024: sp = bx&1, itile = (bx>>1)&63, b = bx>>7. 4 waves/block.
// Per 64-j tile: [A] stage K,V bf16 [B] QK mfma (wave=g) -> arec
//                [C] mix+exp (thread=(l,i,jh), masks direct from mpk) -> pbuf
//                [D] PV mfma (wave=l-pair).  ks and pbuf share one LDS region.
#define IT 16
#define JT 64
#define SPLIT 2
#define JSPAN 512
#define NTL 8
#define KSP 72     // bf16 stride per j-row of ks
#define VTP 72     // bf16 stride per c-row of vt
#define ARP 68     // dword stride per j-row of arec; arec[j][i*4+g]
#define PIP 72     // bf16 stride per i-row of pbuf
#define PLP 1160   // bf16 stride per l-plane of pbuf

__global__ __launch_bounds__(256) void attn_kernel(
    const short* __restrict__ qb, const short* __restrict__ kb,
    const short* __restrict__ vtb, const float* __restrict__ mpk,
    const float* __restrict__ mask_proj,
    float* __restrict__ pnum, float* __restrict__ pden2)
{
  __shared__ short ub[LL * PLP];     // 18560 B: ks (phase B) / pbuf (phases C-D)
  __shared__ short vt[CC * VTP];     // 18432 B
  __shared__ float arec[JT * ARP];   // 17408 B   (total 54400 B -> 3 blocks/CU)
  short* ks = ub;
  short* pbuf = ub;

  const int t = threadIdx.x;
  const int sp = blockIdx.x & 1;
  const int itile = (blockIdx.x >> 1) & 63;
  const int b = blockIdx.x >> 7;
  const int i0 = itile * IT;

  const int w = t >> 6;          // wave id: g (QK), l-pair (PV)
  const int lane = t & 63;
  const int ln = lane & 15;
  const int hq = lane >> 4;

  const int l = t & 7;           // mix roles
  const int mi = (t >> 3) & 15;
  const int jh = t >> 7;

  // Q A-fragment (bf16 direct), K-dim zero-padded 16->32 (hq>=2 zero)
  short8 qf;
  {
    union { short s[8]; short8 v; } qq;
    #pragma unroll
    for (int z = 0; z < 8; ++z) qq.s[z] = 0;
    if (hq < 2)
      qq.v = *(const short8*)(qb + ((long)(b * NN + i0 + ln)) * GD + w * 16 + hq * 8);
    qf = qq.v;
  }
  float yc[3][4];
  #pragma unroll
  for (int m = 0; m < 3; ++m)
    #pragma unroll
    for (int g = 0; g < 4; ++g) yc[m][g] = mask_proj[m * 32 + g * 8 + l];

  const floatx4 zf = {0.f, 0.f, 0.f, 0.f};
  floatx4 pvacc0 = zf, pvacc1 = zf;
  float den = 0.f;

  const short* kbase = kb + (long)b * NN * GD;
  const short* vbase = vtb + (long)b * CC * NN;
  const float* mrow = mpk + (long)(i0 + mi) * NN * 4;

  for (int jt = 0; jt < NTL; ++jt) {
    const int j0 = sp * JSPAN + jt * JT;
    __syncthreads();   // A: prior tile's PV/mix readers done

    #pragma unroll
    for (int it2 = 0; it2 < 2; ++it2) {     // stage K: 64 j x 64 d bf16
      int f = t + it2 * 256;
      int j = f >> 3, dg = f & 7;
      short8 v8 = *(const short8*)(kbase + (long)(j0 + j) * GD + dg * 8);
      *(short8*)(ks + j * KSP + dg * 8) = v8;
    }
    #pragma unroll
    for (int it2 = 0; it2 < 4; ++it2) {     // stage V: 128 c x 64 j bf16 (1024 short8)
      int f = t + it2 * 256;
      int c = f >> 3, sb = f & 7;
      short8 v8 = *(const short8*)(vbase + (long)c * NN + j0 + sb * 8);
      *(short8*)(vt + c * VTP + sb * 8) = v8;
    }
    __syncthreads();   // B: staged

    // ---- QK: wave g = w, 4 j-subtiles ----
    #pragma unroll
    for (int jsub = 0; jsub < 4; ++jsub) {
      union { short s[8]; short8 v; } kk;
      #pragma unroll
      for (int z = 0; z < 8; ++z) kk.s[z] = 0;
      if (hq < 2)
        kk.v = *(const short8*)(ks + (jsub * 16 + ln) * KSP + w * 16 + hq * 8);
      floatx4 at = __builtin_amdgcn_mfma_f32_16x16x32_bf16(qf, kk.v, zf, 0, 0, 0);
      float* ab = arec + (jsub * 16 + ln) * ARP + w;   // arec[j][i*4+g]
      #pragma unroll
      for (int reg = 0; reg < 4; ++reg)
        ab[(hq * 4 + reg) * 4] = at[reg];
    }
    __syncthreads();   // C: arec ready; ks dead -> region becomes pbuf

    // ---- mix + exp -> P bf16 (masks from packed mpk) ----
    {
      const float* mrt = mrow + (long)(j0 + jh * 32) * 4;
      const float* art = arec + (jh * 32) * ARP + mi * 4;
      short* pw = pbuf + l * PLP + mi * PIP + jh * 32;
      union { short s[8]; short8 v; } pj;
      #pragma unroll 8
      for (int jj = 0; jj < 32; ++jj) {
        floatx4 a4 = *(const floatx4*)(art + jj * ARP);
        float4 mk = *(const float4*)(mrt + jj * 4);
        float w0 = mk.x*yc[0][0] + mk.y*yc[1][0] + mk.z*yc[2][0];
        float w1 = mk.x*yc[0][1] + mk.y*yc[1][1] + mk.z*yc[2][1];
        float w2 = mk.x*yc[0][2] + mk.y*yc[1][2] + mk.z*yc[2][2];
        float w3 = mk.x*yc[0][3] + mk.y*yc[1][3] + mk.z*yc[2][3];
        float sc = a4[0]*w0 + a4[1]*w1 + a4[2]*w2 + a4[3]*w3;
        float e = __expf(sc);
        short eb = f2b(e);
        den += b2f(eb);            // denom consistent with bf16 P used in PV
        pj.s[jj & 7] = eb;
        if ((jj & 7) == 7) *(short8*)(pw + (jj & 24)) = pj.v;
      }
    }
    __syncthreads();   // D: pbuf ready

    // ---- PV: wave w -> l = 2w, 2w+1; K=64 via 2 MFMAs each ----
    #pragma unroll
    for (int mf = 0; mf < 2; ++mf) {
      short8 pf0 = *(const short8*)(pbuf + (2*w) * PLP + ln * PIP + mf * 32 + hq * 8);
      short8 vf0 = *(const short8*)(vt + ((2*w) * 16 + ln) * VTP + mf * 32 + hq * 8);
      pvacc0 = __builtin_amdgcn_mfma_f32_16x16x32_bf16(pf0, vf0, pvacc0, 0, 0, 0);
      short8 pf1 = *(const short8*)(pbuf + (2*w+1) * PLP + ln * PIP + mf * 32 + hq * 8);
      short8 vf1 = *(const short8*)(vt + ((2*w+1) * 16 + ln) * VTP + mf * 32 + hq * 8);
      pvacc1 = __builtin_amdgcn_mfma_f32_16x16x32_bf16(pf1, vf1, pvacc1, 0, 0, 0);
    }
  }

  // ---- epilogue: partials ----
  #pragma unroll
  for (int reg = 0; reg < 4; ++reg) {
    long row = ((long)(sp * BB + b)) * NN + i0 + hq * 4 + reg;
    pnum[row * CC + (2*w) * 16 + ln]   = pvacc0[reg];
    pnum[row * CC + (2*w+1) * 16 + ln] = pvacc1[reg];
  }
  pden2[(((long)sp * BB + b) * NN + i0 + mi) * 16 + l * 2 + jh] = den;
}

// ---------------- Kernel C: combine partials ----------------
__global__ __launch_bounds__(256) void reduce_kernel(
    const float* __restrict__ pnum, const float* __restrict__ pden2,
    float* __restrict__ out)
{
  int e4 = blockIdx.x * 256 + threadIdx.x;   // float4 index
  int bi = e4 >> 5;
  int c4 = e4 & 31;
  int l = c4 >> 2;
  const float4* p4 = (const float4*)pnum;
  float4 n0 = p4[e4];
  float4 n1 = p4[e4 + (BB * NN * CC / 4)];
  float den = 0.f;
  #pragma unroll
  for (int s = 0; s < SPLIT; ++s)
    #pragma unroll
    for (int h = 0; h < 2; ++h)
      den += pden2[((long)s * BB * NN + bi) * 16 + l * 2 + h];
  float inv = 1.0f / den;
  float4 o;
  o.x = (n0.x + n1.x) * inv;
  o.y = (n0.y + n1.y) * inv;
  o.z = (n0.z + n1.z) * inv;
  o.w = (n0.w + n1.w) * inv;
  ((float4*)out)[e4] = o;
}

extern "C" void kernel_launch(void* const* d_in, const int* in_sizes, int n_in,
                              void* d_out, int out_size, void* d_ws, size_t ws_size,
                              hipStream_t stream) {
  const float* x         = (const float*)d_in[0];
  const float* masks     = (const float*)d_in[1];
  const float* Wq        = (const float*)d_in[2];
  const float* Wk        = (const float*)d_in[3];
  const float* Wv        = (const float*)d_in[4];
  const float* mask_proj = (const float*)d_in[5];
  float* out = (float*)d_out;

  // ws: qb 1M | kb 1M | vtb 2M | mpk 16M | pnum 8M | pden2 1M  = 29 MB
  char* wsB = (char*)d_ws;
  short* qb    = (short*)(wsB);
  short* kb    = (short*)(wsB + (1l << 20));
  short* vtb   = (short*)(wsB + (2l << 20));
  float* mpk   = (float*)(wsB + (4l << 20));
  float* pnum  = (float*)(wsB + (20l << 20));
  float* pden2 = (float*)(wsB + (28l << 20));

  mpack_kernel<<<(NN * NN) / 256, 256, 0, stream>>>(masks, mpk);
  proj_kernel<<<dim3(256, 4), 256, 0, stream>>>(x, Wq, Wk, Wv, qb, kb, vtb);
  attn_kernel<<<BB * (NN / IT) * SPLIT, 256, 0, stream>>>(qb, kb, vtb, mpk,
                                                          mask_proj, pnum, pden2);
  reduce_kernel<<<(BB * NN * CC / 4) / 256, 256, 0, stream>>>(pnum, pden2, out);
}